// Round 5
// baseline (205.619 us; speedup 1.0000x reference)
//
#include <hip/hip_runtime.h>
#include <cstdint>
#include <cstddef>

typedef __attribute__((ext_vector_type(8))) short bf16x8;
typedef __attribute__((ext_vector_type(4))) float f32x4;

__device__ __forceinline__ unsigned short f2bf(float f) {
  unsigned int u = __builtin_bit_cast(unsigned int, f);
  u += 0x7FFFu + ((u >> 16) & 1u);
  return (unsigned short)(u >> 16);
}
__device__ __forceinline__ float bf2f(unsigned short h) {
  unsigned int u = ((unsigned int)h) << 16;
  return __builtin_bit_cast(float, u);
}

__device__ __forceinline__ void gl_lds16(const unsigned short* g, unsigned short* l) {
  __builtin_amdgcn_global_load_lds(
      (const __attribute__((address_space(1))) unsigned int*)(uintptr_t)g,
      (__attribute__((address_space(3))) unsigned int*)(unsigned int)(uintptr_t)l,
      16, 0, 0);
}

// ---------------- fp32 -> bf16 convert (x) ----------------
__global__ void k_convert(const float* __restrict__ in, unsigned short* __restrict__ out, int n4) {
  int i = blockIdx.x * blockDim.x + threadIdx.x;
  if (i >= n4) return;
  float4 v = reinterpret_cast<const float4*>(in)[i];
  uint2 o;
  o.x = (unsigned int)f2bf(v.x) | ((unsigned int)f2bf(v.y) << 16);
  o.y = (unsigned int)f2bf(v.z) | ((unsigned int)f2bf(v.w) << 16);
  reinterpret_cast<uint2*>(out)[i] = o;
}

// ---------------- transpose + convert W [K][N] fp32 -> [N][K] bf16 ----------------
__global__ void k_wtrans(const float* __restrict__ in, unsigned short* __restrict__ out,
                         int rows, int cols) {
  __shared__ float tile[32][33];
  int c0 = blockIdx.x * 32, r0 = blockIdx.y * 32;
  int tx = threadIdx.x, ty = threadIdx.y;
#pragma unroll
  for (int j = 0; j < 4; j++)
    tile[ty + j * 8][tx] = in[(size_t)(r0 + ty + j * 8) * cols + c0 + tx];
  __syncthreads();
#pragma unroll
  for (int j = 0; j < 4; j++)
    out[(size_t)(c0 + ty + j * 8) * rows + r0 + tx] = f2bf(tile[tx][ty + j * 8]);
}

// ---------------- RoPE cos/sin tables [2048][32] ----------------
__global__ void k_rope_tab(float* __restrict__ ct, float* __restrict__ st) {
  int i = blockIdx.x * blockDim.x + threadIdx.x;  // t*32 + j
  int t = i >> 5, j = i & 31;
  float invf = __powf(10000.0f, -(float)j / 32.0f);
  float ang = (float)t * invf;
  ct[i] = cosf(ang);
  st[i] = sinf(ang);
}

// ---------------- bf16 MFMA GEMM: C[M][N] = A[M][K] * Bt[N][K]^T ----------------
// 128x128 tile, BK=32, 4 waves (2x2), 4x4 16x16x32 frags per wave. (m97 structure)
// T1: bijective XCD-chunked blockIdx swizzle (grid size % 8 == 0 for both launches).
template<int OUT_BF16>
__global__ void k_gemm(const unsigned short* __restrict__ A,
                       const unsigned short* __restrict__ Bt,
                       void* __restrict__ C, int M, int N, int K) {
  __shared__ unsigned short Ta[128 * 32];
  __shared__ unsigned short Tb[128 * 32];
  const int tid = threadIdx.x;
  const int nbx = gridDim.x;
  const int nwg = nbx * gridDim.y;
  const int bid0 = blockIdx.y * nbx + blockIdx.x;
  const int bid = (bid0 & 7) * (nwg >> 3) + (bid0 >> 3);
  const int m0 = (bid / nbx) * 128, n0 = (bid % nbx) * 128;
  const int w = tid >> 6, l = tid & 63;
  const int lr = l & 15, lg = l >> 4;
  const int wm = (w >> 1) * 64, wn = (w & 1) * 64;
  const int ssr = w * 32 + (l >> 2);
  const int ssc = (l & 3) * 8;
  unsigned short* ta0 = &Ta[w * 1024];
  unsigned short* tb0 = &Tb[w * 1024];
  f32x4 acc[4][4] = {};
  for (int k0 = 0; k0 < K; k0 += 32) {
    __syncthreads();
    gl_lds16(&A[(size_t)(m0 + ssr) * K + k0 + ssc],       ta0);
    gl_lds16(&A[(size_t)(m0 + ssr + 16) * K + k0 + ssc],  ta0 + 512);
    gl_lds16(&Bt[(size_t)(n0 + ssr) * K + k0 + ssc],      tb0);
    gl_lds16(&Bt[(size_t)(n0 + ssr + 16) * K + k0 + ssc], tb0 + 512);
    __syncthreads();
    bf16x8 af[4], bfr[4];
#pragma unroll
    for (int i = 0; i < 4; i++)
      af[i] = *(const bf16x8*)&Ta[(wm + i * 16 + lr) * 32 + lg * 8];
#pragma unroll
    for (int j = 0; j < 4; j++)
      bfr[j] = *(const bf16x8*)&Tb[(wn + j * 16 + lr) * 32 + lg * 8];
#pragma unroll
    for (int i = 0; i < 4; i++)
#pragma unroll
      for (int j = 0; j < 4; j++)
        acc[i][j] = __builtin_amdgcn_mfma_f32_16x16x32_bf16(af[i], bfr[j], acc[i][j], 0, 0, 0);
  }
#pragma unroll
  for (int i = 0; i < 4; i++)
#pragma unroll
    for (int j = 0; j < 4; j++)
#pragma unroll
      for (int r = 0; r < 4; r++) {
        int gm = m0 + wm + i * 16 + lg * 4 + r;
        int gn = n0 + wn + j * 16 + lr;
        float v = acc[i][j][r];
        if (OUT_BF16) ((unsigned short*)C)[(size_t)gm * N + gn] = f2bf(v);
        else          ((float*)C)[(size_t)gm * N + gn] = v;
      }
}

// ---------------- RoPE + split qkv -> qh (scaled 0.125*log2e), kh  [B,H,T,D] bf16 ----------
__global__ void k_rope_split(const unsigned short* __restrict__ qkv,
                             const float* __restrict__ ct, const float* __restrict__ st,
                             unsigned short* __restrict__ qh, unsigned short* __restrict__ kh) {
  int idx = blockIdx.x * blockDim.x + threadIdx.x;  // m*1024 + c
  int m = idx >> 10, c = idx & 1023;
  int t = m & 2047, b = m >> 11;
  int h = c >> 6, d = c & 63;
  int j = d & 31;
  float cs = ct[t * 32 + j], sn = st[t * 32 + j];
  size_t rowb = (size_t)m * 3072;
  float qv = bf2f(qkv[rowb + c]);
  float qo = bf2f(qkv[rowb + h * 64 + (d ^ 32)]);
  float kv = bf2f(qkv[rowb + 1024 + c]);
  float ko = bf2f(qkv[rowb + 1024 + h * 64 + (d ^ 32)]);
  float sgn = (d < 32) ? -1.0f : 1.0f;
  float qr = qv * cs + sgn * qo * sn;
  float kr = kv * cs + sgn * ko * sn;
  int bh = b * 16 + h;
  // fold softmax scale (1/8) and the exp->exp2 base change (log2 e) into Q
  qh[(size_t)(bh * 2048 + t) * 64 + d] = f2bf(qr * 0.180336880111120420f);
  kh[(size_t)(bh * 2048 + t) * 64 + d] = f2bf(kr);
}

// ---------------- V transpose: qkv v-part [m][c] -> vt [B,H,D,T] bf16 ----------------
__global__ void k_vtrans(const unsigned short* __restrict__ qkv, unsigned short* __restrict__ vt) {
  __shared__ unsigned short tile[64][72];
  const int bh = blockIdx.y, b = bh >> 4, h = bh & 15;
  const int t0 = blockIdx.x * 64;
  const int tid = threadIdx.x;
  {
    int r = tid >> 2, c = (tid & 3) * 16;
    const unsigned short* src = &qkv[(size_t)(b * 2048 + t0 + r) * 3072 + 2048 + h * 64 + c];
    uint4 v0 = *(const uint4*)src;
    uint4 v1 = *(const uint4*)(src + 8);
    *(uint4*)&tile[r][c] = v0;
    *(uint4*)&tile[r][c + 8] = v1;
  }
  __syncthreads();
#pragma unroll
  for (int q = 0; q < 2; q++) {
    int d = (tid >> 3) + q * 32;
    int tts = (tid & 7) * 8;
    unsigned short vals[8];
#pragma unroll
    for (int e = 0; e < 8; e++) vals[e] = tile[tts + e][d];
    *(uint4*)&vt[((size_t)bh * 64 + d) * 2048 + t0 + tts] = *(uint4*)vals;
  }
}

// ---------------- causal flash attention, barrier-free direct-global fragments --------
// 512 blocks (uniform pair {qt0, 31-qt0} = 33 steps), 256 threads = 4 waves, NO
// __syncthreads anywhere. K/V MFMA A-fragments load straight global->VGPR (lane-
// addressable layouts kh[t][d], vt[d][t]); 4-wave redundancy served by L1/L2 (XCD
// head-locality). K double-buffered one step ahead (unroll-by-2 role swap). P
// round-trip via per-wave LDS (2KB, wave-synchronous). T13 defer-max, T5 setprio.
__global__ __launch_bounds__(256, 2) void k_attn(const unsigned short* __restrict__ qh,
                       const unsigned short* __restrict__ kh,
                       const unsigned short* __restrict__ vt,
                       unsigned short* __restrict__ att) {
  __shared__ unsigned short Pl[4][16 * 64];  // per-wave [q][k]
  const int bid = blockIdx.x;
  const int bh  = ((bid & 7) << 2) | (bid >> 7);   // head-major per XCD
  const int qt0 = (bid >> 3) & 15;
  const int b = bh >> 4, h = bh & 15;
  const int tid = threadIdx.x;
  const int w = tid >> 6, l = tid & 63;
  const int lr = l & 15, lg = l >> 4;
  const unsigned short* qbase = qh + (size_t)bh * 2048 * 64;
  const unsigned short* kbase = kh + (size_t)bh * 2048 * 64;
  const unsigned short* vbase = vt + (size_t)bh * 64 * 2048;
  char* PB = (char*)&Pl[w][0];
  const int swz = (lr & 7) << 4;
  // per-lane fragment bases: K frag (kq,c): kfb + (kv0+16kq)*64 + c*32
  const unsigned short* kfb = kbase + (size_t)lr * 64 + lg * 8;
  // V frag (n,c): vfb + 16n*2048 + kv0 + c*32
  const unsigned short* vfb = vbase + (size_t)lr * 2048 + lg * 8;

  auto run_tile = [&](int qt) {
    const int q0 = qt * 64;
    const int qrow = q0 + w * 16 + lr;
    bf16x8 qa = *(const bf16x8*)&qbase[(size_t)qrow * 64 + lg * 8];
    bf16x8 qb = *(const bf16x8*)&qbase[(size_t)qrow * 64 + 32 + lg * 8];
    float mr = -3.0e38f, ls = 0.0f;
    f32x4 of[4] = {};
    bf16x8 kA[8], kB[8];
#pragma unroll
    for (int i = 0; i < 8; i++)   // i = kq*2 + c
      kA[i] = *(const bf16x8*)&kfb[(size_t)((i >> 1) * 16) * 64 + (i & 1) * 32];

    auto step = [&](int kb, bf16x8 (&kc)[8], bf16x8 (&kn)[8]) {
      const int kv0 = kb * 64;
      // V loads for this step (overlap with QK)
      bf16x8 vf[8];
#pragma unroll
      for (int i = 0; i < 8; i++)  // i = n*2 + c
        vf[i] = *(const bf16x8*)&vfb[(size_t)((i >> 1) * 16) * 2048 + kv0 + (i & 1) * 32];
      f32x4 s[4] = {};
      __builtin_amdgcn_s_setprio(1);
#pragma unroll
      for (int kq = 0; kq < 4; kq++) {
        s[kq] = __builtin_amdgcn_mfma_f32_16x16x32_bf16(kc[kq * 2], qa, s[kq], 0, 0, 0);
        s[kq] = __builtin_amdgcn_mfma_f32_16x16x32_bf16(kc[kq * 2 + 1], qb, s[kq], 0, 0, 0);
      }
      __builtin_amdgcn_s_setprio(0);
      if (kb < qt) {   // prefetch next step's K fragments (lands during softmax/PV)
#pragma unroll
        for (int i = 0; i < 8; i++)
          kn[i] = *(const bf16x8*)&kfb[(size_t)(kv0 + 64 + (i >> 1) * 16) * 64 + (i & 1) * 32];
      }
      if (kb == qt) {  // diagonal block: causal mask
#pragma unroll
        for (int kq = 0; kq < 4; kq++)
#pragma unroll
          for (int r = 0; r < 4; r++)
            if (kv0 + kq * 16 + lg * 4 + r > qrow) s[kq][r] = -3.0e38f;
      }
      float pm = s[0][0];
#pragma unroll
      for (int kq = 0; kq < 4; kq++)
#pragma unroll
        for (int r = 0; r < 4; r++) pm = fmaxf(pm, s[kq][r]);
      pm = fmaxf(pm, __shfl_xor(pm, 16));
      pm = fmaxf(pm, __shfl_xor(pm, 32));
      float psum = 0.0f;
      if (__all(pm <= mr)) {          // T13: running max unchanged -> no rescale pass
#pragma unroll
        for (int kq = 0; kq < 4; kq++)
#pragma unroll
          for (int r = 0; r < 4; r++) {
            float p = __builtin_amdgcn_exp2f(s[kq][r] - mr);
            s[kq][r] = p;
            psum += p;
          }
        psum += __shfl_xor(psum, 16);
        psum += __shfl_xor(psum, 32);
        ls += psum;
      } else {
        float mnew = fmaxf(mr, pm);
        float alpha = __builtin_amdgcn_exp2f(mr - mnew);
        mr = mnew;
#pragma unroll
        for (int kq = 0; kq < 4; kq++)
#pragma unroll
          for (int r = 0; r < 4; r++) {
            float p = __builtin_amdgcn_exp2f(s[kq][r] - mnew);
            s[kq][r] = p;
            psum += p;
          }
        psum += __shfl_xor(psum, 16);
        psum += __shfl_xor(psum, 32);
        ls = ls * alpha + psum;
#pragma unroll
        for (int n = 0; n < 4; n++) {
          of[n][0] *= alpha; of[n][1] *= alpha; of[n][2] *= alpha; of[n][3] *= alpha;
        }
      }
      // P -> per-wave LDS [q][k] (wave-synchronous, no barrier)
#pragma unroll
      for (int kq = 0; kq < 4; kq++) {
        uint2 pk;
        asm("v_cvt_pk_bf16_f32 %0, %1, %2" : "=v"(pk.x) : "v"(s[kq][0]), "v"(s[kq][1]));
        asm("v_cvt_pk_bf16_f32 %0, %1, %2" : "=v"(pk.y) : "v"(s[kq][2]), "v"(s[kq][3]));
        *(uint2*)(PB + ((lr * 128 + (kq * 16 + lg * 4) * 2) ^ swz)) = pk;
      }
      bf16x8 pb0 = *(const bf16x8*)(PB + ((lr * 128 + lg * 16) ^ swz));
      bf16x8 pb1 = *(const bf16x8*)(PB + ((lr * 128 + 64 + lg * 16) ^ swz));
      __builtin_amdgcn_s_setprio(1);
#pragma unroll
      for (int n = 0; n < 4; n++) {
        of[n] = __builtin_amdgcn_mfma_f32_16x16x32_bf16(vf[n * 2],     pb0, of[n], 0, 0, 0);
        of[n] = __builtin_amdgcn_mfma_f32_16x16x32_bf16(vf[n * 2 + 1], pb1, of[n], 0, 0, 0);
      }
      __builtin_amdgcn_s_setprio(0);
    };

    for (int kb = 0; kb <= qt; kb += 2) {
      step(kb, kA, kB);
      if (kb + 1 <= qt) step(kb + 1, kB, kA);
    }

    // normalize + store via per-wave LDS transpose (coalesced 128B rows)
    float inv = 1.0f / ls;
#pragma unroll
    for (int n = 0; n < 4; n++) {
      uint2 pk;
      float o0 = of[n][0] * inv, o1 = of[n][1] * inv, o2 = of[n][2] * inv, o3 = of[n][3] * inv;
      asm("v_cvt_pk_bf16_f32 %0, %1, %2" : "=v"(pk.x) : "v"(o0), "v"(o1));
      asm("v_cvt_pk_bf16_f32 %0, %1, %2" : "=v"(pk.y) : "v"(o2), "v"(o3));
      *(uint2*)(PB + ((lr * 128 + (n * 16 + lg * 4) * 2) ^ swz)) = pk;
    }
    {
      int r2 = l >> 2, c2 = (l & 3) * 16;
      int bo0 = (r2 * 128 + c2 * 2) ^ ((r2 & 7) << 4);
      int bo1 = (r2 * 128 + c2 * 2 + 16) ^ ((r2 & 7) << 4);
      uint4 o0 = *(const uint4*)(PB + bo0);
      uint4 o1 = *(const uint4*)(PB + bo1);
      unsigned short* orow = att + (size_t)(b * 2048 + q0 + w * 16 + r2) * 1024 + h * 64 + c2;
      *(uint4*)orow = o0;
      *(uint4*)(orow + 8) = o1;
    }
  };

  run_tile(qt0);
  run_tile(31 - qt0);
}

extern "C" void kernel_launch(void* const* d_in, const int* in_sizes, int n_in,
                              void* d_out, int out_size, void* d_ws, size_t ws_size,
                              hipStream_t stream) {
  const float* x     = (const float*)d_in[0];
  const float* Wqkv  = (const float*)d_in[1];
  const float* Wproj = (const float*)d_in[2];
  float* out = (float*)d_out;

  char* ws = (char*)d_ws;
  size_t off = 0;
  auto alloc = [&](size_t bytes) { void* p = ws + off; off += (bytes + 255) & ~(size_t)255; return p; };
  unsigned short* xb   = (unsigned short*)alloc((size_t)4096 * 1024 * 2);
  unsigned short* wqt  = (unsigned short*)alloc((size_t)3072 * 1024 * 2);
  unsigned short* wpt  = (unsigned short*)alloc((size_t)1024 * 1024 * 2);
  unsigned short* qkvf = (unsigned short*)alloc((size_t)4096 * 3072 * 2);
  unsigned short* qh   = (unsigned short*)alloc((size_t)32 * 2048 * 64 * 2);
  unsigned short* kh   = (unsigned short*)alloc((size_t)32 * 2048 * 64 * 2);
  unsigned short* vt   = (unsigned short*)alloc((size_t)32 * 64 * 2048 * 2);
  unsigned short* att  = (unsigned short*)alloc((size_t)4096 * 1024 * 2);
  float* ctab = (float*)alloc((size_t)2048 * 32 * 4);
  float* stab = (float*)alloc((size_t)2048 * 32 * 4);

  k_convert<<<4096, 256, 0, stream>>>(x, xb, 4096 * 1024 / 4);
  k_wtrans<<<dim3(96, 32), dim3(32, 8), 0, stream>>>(Wqkv, wqt, 1024, 3072);
  k_wtrans<<<dim3(32, 32), dim3(32, 8), 0, stream>>>(Wproj, wpt, 1024, 1024);
  k_rope_tab<<<256, 256, 0, stream>>>(ctab, stab);
  k_gemm<1><<<dim3(24, 32), 256, 0, stream>>>(xb, wqt, qkvf, 4096, 3072, 1024);
  k_rope_split<<<16384, 256, 0, stream>>>(qkvf, ctab, stab, qh, kh);
  k_vtrans<<<dim3(32, 32), 256, 0, stream>>>(qkvf, vt);
  k_attn<<<512, 256, 0, stream>>>(qh, kh, vt, att);
  k_gemm<0><<<dim3(8, 32), 256, 0, stream>>>(att, wpt, out, 4096, 1024, 1024);
}

// Round 6
// 142.629 us; speedup vs baseline: 1.4416x; 1.4416x over previous
//
#include <hip/hip_runtime.h>
#include <cstdint>
#include <cstddef>

typedef __attribute__((ext_vector_type(8))) short bf16x8;
typedef __attribute__((ext_vector_type(4))) float f32x4;

__device__ __forceinline__ unsigned short f2bf(float f) {
  unsigned int u = __builtin_bit_cast(unsigned int, f);
  u += 0x7FFFu + ((u >> 16) & 1u);
  return (unsigned short)(u >> 16);
}
__device__ __forceinline__ float bf2f(unsigned short h) {
  unsigned int u = ((unsigned int)h) << 16;
  return __builtin_bit_cast(float, u);
}

__device__ __forceinline__ void gl_lds16(const unsigned short* g, unsigned short* l) {
  __builtin_amdgcn_global_load_lds(
      (const __attribute__((address_space(1))) unsigned int*)(uintptr_t)g,
      (__attribute__((address_space(3))) unsigned int*)(unsigned int)(uintptr_t)l,
      16, 0, 0);
}

// ---------------- fp32 -> bf16 convert (x) ----------------
__global__ void k_convert(const float* __restrict__ in, unsigned short* __restrict__ out, int n4) {
  int i = blockIdx.x * blockDim.x + threadIdx.x;
  if (i >= n4) return;
  float4 v = reinterpret_cast<const float4*>(in)[i];
  uint2 o;
  o.x = (unsigned int)f2bf(v.x) | ((unsigned int)f2bf(v.y) << 16);
  o.y = (unsigned int)f2bf(v.z) | ((unsigned int)f2bf(v.w) << 16);
  reinterpret_cast<uint2*>(out)[i] = o;
}

// ---------------- transpose + convert W [K][N] fp32 -> [N][K] bf16 ----------------
__global__ void k_wtrans(const float* __restrict__ in, unsigned short* __restrict__ out,
                         int rows, int cols) {
  __shared__ float tile[32][33];
  int c0 = blockIdx.x * 32, r0 = blockIdx.y * 32;
  int tx = threadIdx.x, ty = threadIdx.y;
#pragma unroll
  for (int j = 0; j < 4; j++)
    tile[ty + j * 8][tx] = in[(size_t)(r0 + ty + j * 8) * cols + c0 + tx];
  __syncthreads();
#pragma unroll
  for (int j = 0; j < 4; j++)
    out[(size_t)(c0 + ty + j * 8) * rows + r0 + tx] = f2bf(tile[tx][ty + j * 8]);
}

// ---------------- RoPE cos/sin tables [2048][32] ----------------
__global__ void k_rope_tab(float* __restrict__ ct, float* __restrict__ st) {
  int i = blockIdx.x * blockDim.x + threadIdx.x;  // t*32 + j
  int t = i >> 5, j = i & 31;
  float invf = __powf(10000.0f, -(float)j / 32.0f);
  float ang = (float)t * invf;
  ct[i] = cosf(ang);
  st[i] = sinf(ang);
}

// ---------------- bf16 MFMA GEMM: C[M][N] = A[M][K] * Bt[N][K]^T ----------------
// 128x128 tile, BK=32, 4 waves (2x2), 4x4 16x16x32 frags per wave. (m97 structure)
// T1: bijective XCD-chunked blockIdx swizzle (grid size % 8 == 0 for both launches).
template<int OUT_BF16>
__global__ void k_gemm(const unsigned short* __restrict__ A,
                       const unsigned short* __restrict__ Bt,
                       void* __restrict__ C, int M, int N, int K) {
  __shared__ unsigned short Ta[128 * 32];
  __shared__ unsigned short Tb[128 * 32];
  const int tid = threadIdx.x;
  const int nbx = gridDim.x;
  const int nwg = nbx * gridDim.y;
  const int bid0 = blockIdx.y * nbx + blockIdx.x;
  const int bid = (bid0 & 7) * (nwg >> 3) + (bid0 >> 3);
  const int m0 = (bid / nbx) * 128, n0 = (bid % nbx) * 128;
  const int w = tid >> 6, l = tid & 63;
  const int lr = l & 15, lg = l >> 4;
  const int wm = (w >> 1) * 64, wn = (w & 1) * 64;
  const int ssr = w * 32 + (l >> 2);
  const int ssc = (l & 3) * 8;
  unsigned short* ta0 = &Ta[w * 1024];
  unsigned short* tb0 = &Tb[w * 1024];
  f32x4 acc[4][4] = {};
  for (int k0 = 0; k0 < K; k0 += 32) {
    __syncthreads();
    gl_lds16(&A[(size_t)(m0 + ssr) * K + k0 + ssc],       ta0);
    gl_lds16(&A[(size_t)(m0 + ssr + 16) * K + k0 + ssc],  ta0 + 512);
    gl_lds16(&Bt[(size_t)(n0 + ssr) * K + k0 + ssc],      tb0);
    gl_lds16(&Bt[(size_t)(n0 + ssr + 16) * K + k0 + ssc], tb0 + 512);
    __syncthreads();
    bf16x8 af[4], bfr[4];
#pragma unroll
    for (int i = 0; i < 4; i++)
      af[i] = *(const bf16x8*)&Ta[(wm + i * 16 + lr) * 32 + lg * 8];
#pragma unroll
    for (int j = 0; j < 4; j++)
      bfr[j] = *(const bf16x8*)&Tb[(wn + j * 16 + lr) * 32 + lg * 8];
#pragma unroll
    for (int i = 0; i < 4; i++)
#pragma unroll
      for (int j = 0; j < 4; j++)
        acc[i][j] = __builtin_amdgcn_mfma_f32_16x16x32_bf16(af[i], bfr[j], acc[i][j], 0, 0, 0);
  }
#pragma unroll
  for (int i = 0; i < 4; i++)
#pragma unroll
    for (int j = 0; j < 4; j++)
#pragma unroll
      for (int r = 0; r < 4; r++) {
        int gm = m0 + wm + i * 16 + lg * 4 + r;
        int gn = n0 + wn + j * 16 + lr;
        float v = acc[i][j][r];
        if (OUT_BF16) ((unsigned short*)C)[(size_t)gm * N + gn] = f2bf(v);
        else          ((float*)C)[(size_t)gm * N + gn] = v;
      }
}

// ---------------- RoPE + split qkv -> qh (scaled 0.125*log2e), kh  [B,H,T,D] bf16 ----------
__global__ void k_rope_split(const unsigned short* __restrict__ qkv,
                             const float* __restrict__ ct, const float* __restrict__ st,
                             unsigned short* __restrict__ qh, unsigned short* __restrict__ kh) {
  int idx = blockIdx.x * blockDim.x + threadIdx.x;  // m*1024 + c
  int m = idx >> 10, c = idx & 1023;
  int t = m & 2047, b = m >> 11;
  int h = c >> 6, d = c & 63;
  int j = d & 31;
  float cs = ct[t * 32 + j], sn = st[t * 32 + j];
  size_t rowb = (size_t)m * 3072;
  float qv = bf2f(qkv[rowb + c]);
  float qo = bf2f(qkv[rowb + h * 64 + (d ^ 32)]);
  float kv = bf2f(qkv[rowb + 1024 + c]);
  float ko = bf2f(qkv[rowb + 1024 + h * 64 + (d ^ 32)]);
  float sgn = (d < 32) ? -1.0f : 1.0f;
  float qr = qv * cs + sgn * qo * sn;
  float kr = kv * cs + sgn * ko * sn;
  int bh = b * 16 + h;
  // fold softmax scale (1/8) and the exp->exp2 base change (log2 e) into Q
  qh[(size_t)(bh * 2048 + t) * 64 + d] = f2bf(qr * 0.180336880111120420f);
  kh[(size_t)(bh * 2048 + t) * 64 + d] = f2bf(kr);
}

// ---------------- V transpose: qkv v-part [m][c] -> vt [B,H,D,T] bf16 ----------------
__global__ void k_vtrans(const unsigned short* __restrict__ qkv, unsigned short* __restrict__ vt) {
  __shared__ unsigned short tile[64][72];
  const int bh = blockIdx.y, b = bh >> 4, h = bh & 15;
  const int t0 = blockIdx.x * 64;
  const int tid = threadIdx.x;
  {
    int r = tid >> 2, c = (tid & 3) * 16;
    const unsigned short* src = &qkv[(size_t)(b * 2048 + t0 + r) * 3072 + 2048 + h * 64 + c];
    uint4 v0 = *(const uint4*)src;
    uint4 v1 = *(const uint4*)(src + 8);
    *(uint4*)&tile[r][c] = v0;
    *(uint4*)&tile[r][c + 8] = v1;
  }
  __syncthreads();
#pragma unroll
  for (int q = 0; q < 2; q++) {
    int d = (tid >> 3) + q * 32;
    int tts = (tid & 7) * 8;
    unsigned short vals[8];
#pragma unroll
    for (int e = 0; e < 8; e++) vals[e] = tile[tts + e][d];
    *(uint4*)&vt[((size_t)bh * 64 + d) * 2048 + t0 + tts] = *(uint4*)vals;
  }
}

// ---------------- causal flash attention: 128-row q-tiles, 32 q-rows/wave ----------
// 256 blocks = 1/CU, 4 waves. Block handles q-tile pair {a, 15-a} sequentially ->
// exactly 34 KV-64 steps per block (uniform). Wave w owns rows [q0+32w, q0+32w+32)
// as TWO 16-col fragment sets sharing the same K/V fragment reads (2x LDS
// amortization vs 16 rows/wave). Swapped QK^T, reg-prefetch staging (T14),
// defer-max (T13), setprio (T5), XOR-swizzled LDS (G4). XCD head-locality: xcd
// bid&7 owns heads [4*xcd, 4*xcd+4).
__global__ __launch_bounds__(256, 2) void k_attn(const unsigned short* __restrict__ qh,
                       const unsigned short* __restrict__ kh,
                       const unsigned short* __restrict__ vt,
                       unsigned short* __restrict__ att) {
  __shared__ unsigned short Kl[64 * 64];    // [k][d]
  __shared__ unsigned short Vl[64 * 64];    // [d][k]  (V^T)
  __shared__ unsigned short Pl[4][32 * 64]; // per-wave [q_local 0..31][k]
  const int bid = blockIdx.x;
  const int p = bid >> 3;
  const int bh = ((bid & 7) << 2) | (p >> 3);
  const int a = p & 7;
  const int b = bh >> 4, h = bh & 15;
  const int tid = threadIdx.x;
  const int w = tid >> 6, l = tid & 63;
  const int lr = l & 15, lg = l >> 4;
  const unsigned short* qbase = qh + (size_t)bh * 2048 * 64;
  const unsigned short* kbase = kh + (size_t)bh * 2048 * 64;
  const unsigned short* vbase = vt + (size_t)bh * 64 * 2048;
  char* KB = (char*)Kl;
  char* VB = (char*)Vl;
  char* PB = (char*)&Pl[w][0];
  const int swz = (lr & 7) << 4;
  const int sr = tid >> 2, sc = (tid & 3) * 16;
  const int sb0 = (sr * 128 + sc * 2) ^ ((sr & 7) << 4);
  const int sb1 = (sr * 128 + sc * 2 + 16) ^ ((sr & 7) << 4);

  uint4 ka0, ka1, va0, va1;   // in-flight K/V staging chunk (T14)
  auto issue = [&](int kv0) {
    const unsigned short* ksrc = &kbase[(size_t)(kv0 + sr) * 64 + sc];
    const unsigned short* vsrc = &vbase[(size_t)sr * 2048 + kv0 + sc];
    ka0 = *(const uint4*)ksrc; ka1 = *(const uint4*)(ksrc + 8);
    va0 = *(const uint4*)vsrc; va1 = *(const uint4*)(vsrc + 8);
  };

  auto run_tile = [&](int qt) {
    const int q0 = qt * 128;
    const int wq = q0 + 32 * w;
    const int qrow0 = wq + lr;        // colset 0 rows
    const int qrow1 = wq + 16 + lr;   // colset 1 rows
    bf16x8 qa0 = *(const bf16x8*)&qbase[(size_t)qrow0 * 64 + lg * 8];
    bf16x8 qb0 = *(const bf16x8*)&qbase[(size_t)qrow0 * 64 + 32 + lg * 8];
    bf16x8 qa1 = *(const bf16x8*)&qbase[(size_t)qrow1 * 64 + lg * 8];
    bf16x8 qb1 = *(const bf16x8*)&qbase[(size_t)qrow1 * 64 + 32 + lg * 8];
    float mr0 = -3.0e38f, ls0 = 0.0f, mr1 = -3.0e38f, ls1 = 0.0f;
    f32x4 of0[4] = {}, of1[4] = {};
    const int nkv = 2 * qt + 2;

    issue(0);
    for (int kb = 0; kb < nkv; kb++) {
      const int kv0 = kb * 64;
      __syncthreads();
      *(uint4*)(KB + sb0) = ka0;  *(uint4*)(KB + sb1) = ka1;
      *(uint4*)(VB + sb0) = va0;  *(uint4*)(VB + sb1) = va1;
      __syncthreads();
      if (kb + 1 < nkv) issue((kb + 1) * 64);
      if (kv0 > wq + 31) continue;   // this wave fully masked (barriers already done)

      // QK^T (swapped): shared K-frags feed both colsets
      f32x4 s0[4] = {}, s1[4] = {};
      __builtin_amdgcn_s_setprio(1);
#pragma unroll
      for (int kq = 0; kq < 4; kq++) {
        bf16x8 kf0 = *(const bf16x8*)(KB + (((kq * 16 + lr) * 128 + lg * 16) ^ swz));
        bf16x8 kf1 = *(const bf16x8*)(KB + (((kq * 16 + lr) * 128 + 64 + lg * 16) ^ swz));
        s0[kq] = __builtin_amdgcn_mfma_f32_16x16x32_bf16(kf0, qa0, s0[kq], 0, 0, 0);
        s1[kq] = __builtin_amdgcn_mfma_f32_16x16x32_bf16(kf0, qa1, s1[kq], 0, 0, 0);
        s0[kq] = __builtin_amdgcn_mfma_f32_16x16x32_bf16(kf1, qb0, s0[kq], 0, 0, 0);
        s1[kq] = __builtin_amdgcn_mfma_f32_16x16x32_bf16(kf1, qb1, s1[kq], 0, 0, 0);
      }
      __builtin_amdgcn_s_setprio(0);
      if (kv0 + 63 > wq) {  // diagonal region: elementwise causal mask
#pragma unroll
        for (int kq = 0; kq < 4; kq++)
#pragma unroll
          for (int r = 0; r < 4; r++) {
            int krow = kv0 + kq * 16 + lg * 4 + r;
            if (krow > qrow0) s0[kq][r] = -3.0e38f;
            if (krow > qrow1) s1[kq][r] = -3.0e38f;
          }
      }
      // online softmax per colset (base-2; scale folded into Q); T13 defer-max
      {
        float pm = s0[0][0];
#pragma unroll
        for (int kq = 0; kq < 4; kq++)
#pragma unroll
          for (int r = 0; r < 4; r++) pm = fmaxf(pm, s0[kq][r]);
        pm = fmaxf(pm, __shfl_xor(pm, 16));
        pm = fmaxf(pm, __shfl_xor(pm, 32));
        float psum = 0.0f;
        if (__all(pm <= mr0)) {
#pragma unroll
          for (int kq = 0; kq < 4; kq++)
#pragma unroll
            for (int r = 0; r < 4; r++) {
              float pv = __builtin_amdgcn_exp2f(s0[kq][r] - mr0);
              s0[kq][r] = pv; psum += pv;
            }
          psum += __shfl_xor(psum, 16);
          psum += __shfl_xor(psum, 32);
          ls0 += psum;
        } else {
          float mnew = fmaxf(mr0, pm);
          float alpha = __builtin_amdgcn_exp2f(mr0 - mnew);
          mr0 = mnew;
#pragma unroll
          for (int kq = 0; kq < 4; kq++)
#pragma unroll
            for (int r = 0; r < 4; r++) {
              float pv = __builtin_amdgcn_exp2f(s0[kq][r] - mnew);
              s0[kq][r] = pv; psum += pv;
            }
          psum += __shfl_xor(psum, 16);
          psum += __shfl_xor(psum, 32);
          ls0 = ls0 * alpha + psum;
#pragma unroll
          for (int n = 0; n < 4; n++) {
            of0[n][0] *= alpha; of0[n][1] *= alpha; of0[n][2] *= alpha; of0[n][3] *= alpha;
          }
        }
      }
      {
        float pm = s1[0][0];
#pragma unroll
        for (int kq = 0; kq < 4; kq++)
#pragma unroll
          for (int r = 0; r < 4; r++) pm = fmaxf(pm, s1[kq][r]);
        pm = fmaxf(pm, __shfl_xor(pm, 16));
        pm = fmaxf(pm, __shfl_xor(pm, 32));
        float psum = 0.0f;
        if (__all(pm <= mr1)) {
#pragma unroll
          for (int kq = 0; kq < 4; kq++)
#pragma unroll
            for (int r = 0; r < 4; r++) {
              float pv = __builtin_amdgcn_exp2f(s1[kq][r] - mr1);
              s1[kq][r] = pv; psum += pv;
            }
          psum += __shfl_xor(psum, 16);
          psum += __shfl_xor(psum, 32);
          ls1 += psum;
        } else {
          float mnew = fmaxf(mr1, pm);
          float alpha = __builtin_amdgcn_exp2f(mr1 - mnew);
          mr1 = mnew;
#pragma unroll
          for (int kq = 0; kq < 4; kq++)
#pragma unroll
            for (int r = 0; r < 4; r++) {
              float pv = __builtin_amdgcn_exp2f(s1[kq][r] - mnew);
              s1[kq][r] = pv; psum += pv;
            }
          psum += __shfl_xor(psum, 16);
          psum += __shfl_xor(psum, 32);
          ls1 = ls1 * alpha + psum;
#pragma unroll
          for (int n = 0; n < 4; n++) {
            of1[n][0] *= alpha; of1[n][1] *= alpha; of1[n][2] *= alpha; of1[n][3] *= alpha;
          }
        }
      }
      // P -> per-wave LDS [q_local][k]: colset0 rows lr, colset1 rows 16+lr
#pragma unroll
      for (int kq = 0; kq < 4; kq++) {
        uint2 pk0, pk1;
        asm("v_cvt_pk_bf16_f32 %0, %1, %2" : "=v"(pk0.x) : "v"(s0[kq][0]), "v"(s0[kq][1]));
        asm("v_cvt_pk_bf16_f32 %0, %1, %2" : "=v"(pk0.y) : "v"(s0[kq][2]), "v"(s0[kq][3]));
        asm("v_cvt_pk_bf16_f32 %0, %1, %2" : "=v"(pk1.x) : "v"(s1[kq][0]), "v"(s1[kq][1]));
        asm("v_cvt_pk_bf16_f32 %0, %1, %2" : "=v"(pk1.y) : "v"(s1[kq][2]), "v"(s1[kq][3]));
        *(uint2*)(PB + ((lr * 128 + (kq * 16 + lg * 4) * 2) ^ swz)) = pk0;
        *(uint2*)(PB + (((16 + lr) * 128 + (kq * 16 + lg * 4) * 2) ^ swz)) = pk1;
      }
      bf16x8 p00 = *(const bf16x8*)(PB + ((lr * 128 + lg * 16) ^ swz));
      bf16x8 p10 = *(const bf16x8*)(PB + ((lr * 128 + 64 + lg * 16) ^ swz));
      bf16x8 p01 = *(const bf16x8*)(PB + (((16 + lr) * 128 + lg * 16) ^ swz));
      bf16x8 p11 = *(const bf16x8*)(PB + (((16 + lr) * 128 + 64 + lg * 16) ^ swz));
      // O^T += V^T * P^T  (shared V-frags feed both colsets)
      __builtin_amdgcn_s_setprio(1);
#pragma unroll
      for (int n = 0; n < 4; n++) {
        bf16x8 vf0 = *(const bf16x8*)(VB + (((n * 16 + lr) * 128 + lg * 16) ^ swz));
        bf16x8 vf1 = *(const bf16x8*)(VB + (((n * 16 + lr) * 128 + 64 + lg * 16) ^ swz));
        of0[n] = __builtin_amdgcn_mfma_f32_16x16x32_bf16(vf0, p00, of0[n], 0, 0, 0);
        of1[n] = __builtin_amdgcn_mfma_f32_16x16x32_bf16(vf0, p01, of1[n], 0, 0, 0);
        of0[n] = __builtin_amdgcn_mfma_f32_16x16x32_bf16(vf1, p10, of0[n], 0, 0, 0);
        of1[n] = __builtin_amdgcn_mfma_f32_16x16x32_bf16(vf1, p11, of1[n], 0, 0, 0);
      }
      __builtin_amdgcn_s_setprio(0);
    }

    // normalize + store via per-wave LDS transpose (32 rows, coalesced 128B rows)
    float inv0 = 1.0f / ls0, inv1 = 1.0f / ls1;
#pragma unroll
    for (int n = 0; n < 4; n++) {
      uint2 pk0, pk1;
      float a0 = of0[n][0] * inv0, a1 = of0[n][1] * inv0, a2 = of0[n][2] * inv0, a3 = of0[n][3] * inv0;
      float c0 = of1[n][0] * inv1, c1 = of1[n][1] * inv1, c2 = of1[n][2] * inv1, c3 = of1[n][3] * inv1;
      asm("v_cvt_pk_bf16_f32 %0, %1, %2" : "=v"(pk0.x) : "v"(a0), "v"(a1));
      asm("v_cvt_pk_bf16_f32 %0, %1, %2" : "=v"(pk0.y) : "v"(a2), "v"(a3));
      asm("v_cvt_pk_bf16_f32 %0, %1, %2" : "=v"(pk1.x) : "v"(c0), "v"(c1));
      asm("v_cvt_pk_bf16_f32 %0, %1, %2" : "=v"(pk1.y) : "v"(c2), "v"(c3));
      *(uint2*)(PB + ((lr * 128 + (n * 16 + lg * 4) * 2) ^ swz)) = pk0;
      *(uint2*)(PB + (((16 + lr) * 128 + (n * 16 + lg * 4) * 2) ^ swz)) = pk1;
    }
    {
      int r2 = l >> 2, c2 = (l & 3) * 16;
#pragma unroll
      for (int half = 0; half < 2; half++) {
        int row = half * 16 + r2;
        int bo0 = (row * 128 + c2 * 2) ^ ((row & 7) << 4);
        int bo1 = (row * 128 + c2 * 2 + 16) ^ ((row & 7) << 4);
        uint4 o0 = *(const uint4*)(PB + bo0);
        uint4 o1 = *(const uint4*)(PB + bo1);
        unsigned short* orow = att + (size_t)(b * 2048 + wq + row) * 1024 + h * 64 + c2;
        *(uint4*)orow = o0;
        *(uint4*)(orow + 8) = o1;
      }
    }
  };

  run_tile(a);
  run_tile(15 - a);
}

extern "C" void kernel_launch(void* const* d_in, const int* in_sizes, int n_in,
                              void* d_out, int out_size, void* d_ws, size_t ws_size,
                              hipStream_t stream) {
  const float* x     = (const float*)d_in[0];
  const float* Wqkv  = (const float*)d_in[1];
  const float* Wproj = (const float*)d_in[2];
  float* out = (float*)d_out;

  char* ws = (char*)d_ws;
  size_t off = 0;
  auto alloc = [&](size_t bytes) { void* p = ws + off; off += (bytes + 255) & ~(size_t)255; return p; };
  unsigned short* xb   = (unsigned short*)alloc((size_t)4096 * 1024 * 2);
  unsigned short* wqt  = (unsigned short*)alloc((size_t)3072 * 1024 * 2);
  unsigned short* wpt  = (unsigned short*)alloc((size_t)1024 * 1024 * 2);
  unsigned short* qkvf = (unsigned short*)alloc((size_t)4096 * 3072 * 2);
  unsigned short* qh   = (unsigned short*)alloc((size_t)32 * 2048 * 64 * 2);
  unsigned short* kh   = (unsigned short*)alloc((size_t)32 * 2048 * 64 * 2);
  unsigned short* vt   = (unsigned short*)alloc((size_t)32 * 64 * 2048 * 2);
  unsigned short* att  = (unsigned short*)alloc((size_t)4096 * 1024 * 2);
  float* ctab = (float*)alloc((size_t)2048 * 32 * 4);
  float* stab = (float*)alloc((size_t)2048 * 32 * 4);

  k_convert<<<4096, 256, 0, stream>>>(x, xb, 4096 * 1024 / 4);
  k_wtrans<<<dim3(96, 32), dim3(32, 8), 0, stream>>>(Wqkv, wqt, 1024, 3072);
  k_wtrans<<<dim3(32, 32), dim3(32, 8), 0, stream>>>(Wproj, wpt, 1024, 1024);
  k_rope_tab<<<256, 256, 0, stream>>>(ctab, stab);
  k_gemm<1><<<dim3(24, 32), 256, 0, stream>>>(xb, wqt, qkvf, 4096, 3072, 1024);
  k_rope_split<<<16384, 256, 0, stream>>>(qkvf, ctab, stab, qh, kh);
  k_vtrans<<<dim3(32, 32), 256, 0, stream>>>(qkvf, vt);
  k_attn<<<256, 256, 0, stream>>>(qh, kh, vt, att);
  k_gemm<0><<<dim3(8, 32), 256, 0, stream>>>(att, wpt, out, 4096, 1024, 1024);
}

// Round 7
// 105.004 us; speedup vs baseline: 1.9582x; 1.3583x over previous
//
#include <hip/hip_runtime.h>
#include <cstdint>
#include <cstddef>

typedef __attribute__((ext_vector_type(8))) short bf16x8;
typedef __attribute__((ext_vector_type(4))) float f32x4;

__device__ __forceinline__ unsigned short f2bf(float f) {
  unsigned int u = __builtin_bit_cast(unsigned int, f);
  u += 0x7FFFu + ((u >> 16) & 1u);
  return (unsigned short)(u >> 16);
}
__device__ __forceinline__ float bf2f(unsigned short h) {
  unsigned int u = ((unsigned int)h) << 16;
  return __builtin_bit_cast(float, u);
}

__device__ __forceinline__ void gl_lds16(const unsigned short* g, unsigned short* l) {
  __builtin_amdgcn_global_load_lds(
      (const __attribute__((address_space(1))) unsigned int*)(uintptr_t)g,
      (__attribute__((address_space(3))) unsigned int*)(unsigned int)(uintptr_t)l,
      16, 0, 0);
}

// ============ k_prep: convert(x) + wtrans(Wqkv) + wtrans(Wproj) + rope table ============
// grid 8448 x 256: [0,4096) convert, [4096,7168) wtrans qkv, [7168,8192) wtrans proj,
// [8192,8448) cos/sin table (interleaved float2 [2048][32]).
__global__ void k_prep(const float* __restrict__ x,
                       const float* __restrict__ Wqkv,
                       const float* __restrict__ Wproj,
                       unsigned short* __restrict__ xb,
                       unsigned short* __restrict__ wqt,
                       unsigned short* __restrict__ wpt,
                       float2* __restrict__ cstab) {
  __shared__ float tile[32][33];
  const int bid = blockIdx.x, tid = threadIdx.x;
  if (bid < 4096) {
    int i = bid * 256 + tid;
    float4 v = reinterpret_cast<const float4*>(x)[i];
    uint2 o;
    o.x = (unsigned int)f2bf(v.x) | ((unsigned int)f2bf(v.y) << 16);
    o.y = (unsigned int)f2bf(v.z) | ((unsigned int)f2bf(v.w) << 16);
    reinterpret_cast<uint2*>(xb)[i] = o;
  } else if (bid < 8192) {
    const float* in; unsigned short* out; int rows, cols, bx, by;
    if (bid < 7168) { in = Wqkv; out = wqt; rows = 1024; cols = 3072; bx = (bid - 4096) % 96; by = (bid - 4096) / 96; }
    else            { in = Wproj; out = wpt; rows = 1024; cols = 1024; bx = (bid - 7168) % 32; by = (bid - 7168) / 32; }
    int c0 = bx * 32, r0 = by * 32;
    int tx = tid & 31, ty = tid >> 5;
#pragma unroll
    for (int j = 0; j < 4; j++)
      tile[ty + j * 8][tx] = in[(size_t)(r0 + ty + j * 8) * cols + c0 + tx];
    __syncthreads();
#pragma unroll
    for (int j = 0; j < 4; j++)
      out[(size_t)(c0 + ty + j * 8) * rows + r0 + tx] = f2bf(tile[tx][ty + j * 8]);
  } else {
    int i = (bid - 8192) * 256 + tid;   // t*32 + j
    int t = i >> 5, j = i & 31;
    float invf = __powf(10000.0f, -(float)j / 32.0f);
    float ang = (float)t * invf;
    cstab[i] = make_float2(cosf(ang), sinf(ang));
  }
}

// ============ qkv GEMM with fused RoPE/head-split/V-transpose epilogue ============
// M=4096, N=3072, K=1024. 128x128 tile, BK=32, 4 waves, m97 staging. T1 XCD swizzle.
// Epilogue: block's 128 cols lie wholly in q / k / v region (1024%128==0). A wave's
// 64-col span is one head; rotate-half partner d^32 = frag j^2, same lane. q scaled
// by 0.125*log2e (softmax scale + exp2 base change, consumed by k_attn).
__global__ void k_gemm_qkv(const unsigned short* __restrict__ A,
                           const unsigned short* __restrict__ Bt,
                           const float2* __restrict__ cstab,
                           unsigned short* __restrict__ qh,
                           unsigned short* __restrict__ kh,
                           unsigned short* __restrict__ vt) {
  const int K = 1024;
  __shared__ unsigned short Ta[128 * 32];
  __shared__ unsigned short Tb[128 * 32];
  const int tid = threadIdx.x;
  const int bid0 = blockIdx.y * 24 + blockIdx.x;
  const int bid = (bid0 & 7) * 96 + (bid0 >> 3);
  const int m0 = (bid / 24) * 128, n0 = (bid % 24) * 128;
  const int w = tid >> 6, l = tid & 63;
  const int lr = l & 15, lg = l >> 4;
  const int wm = (w >> 1) * 64, wn = (w & 1) * 64;
  const int ssr = w * 32 + (l >> 2);
  const int ssc = (l & 3) * 8;
  unsigned short* ta0 = &Ta[w * 1024];
  unsigned short* tb0 = &Tb[w * 1024];
  f32x4 acc[4][4] = {};
  for (int k0 = 0; k0 < K; k0 += 32) {
    __syncthreads();
    gl_lds16(&A[(size_t)(m0 + ssr) * K + k0 + ssc],       ta0);
    gl_lds16(&A[(size_t)(m0 + ssr + 16) * K + k0 + ssc],  ta0 + 512);
    gl_lds16(&Bt[(size_t)(n0 + ssr) * K + k0 + ssc],      tb0);
    gl_lds16(&Bt[(size_t)(n0 + ssr + 16) * K + k0 + ssc], tb0 + 512);
    __syncthreads();
    bf16x8 af[4], bfr[4];
#pragma unroll
    for (int i = 0; i < 4; i++)
      af[i] = *(const bf16x8*)&Ta[(wm + i * 16 + lr) * 32 + lg * 8];
#pragma unroll
    for (int j = 0; j < 4; j++)
      bfr[j] = *(const bf16x8*)&Tb[(wn + j * 16 + lr) * 32 + lg * 8];
#pragma unroll
    for (int i = 0; i < 4; i++)
#pragma unroll
      for (int j = 0; j < 4; j++)
        acc[i][j] = __builtin_amdgcn_mfma_f32_16x16x32_bf16(af[i], bfr[j], acc[i][j], 0, 0, 0);
  }
  const int part = n0 >> 10;                 // 0=q, 1=k, 2=v (block-uniform)
  const int hbase = (n0 & 1023) + wn;        // multiple of 64
  if (part < 2) {
    unsigned short* dst = part ? kh : qh;
    const float scale = part ? 1.0f : 0.180336880111120420f;
#pragma unroll
    for (int i = 0; i < 4; i++) {
#pragma unroll
      for (int r = 0; r < 4; r++) {
        int gm = m0 + wm + i * 16 + lg * 4 + r;
        int t = gm & 2047, b = gm >> 11;
        float2 cs0 = cstab[t * 32 + lr];        // d&31 == lr      (j even)
        float2 cs1 = cstab[t * 32 + 16 + lr];   // d&31 == lr+16   (j odd)
#pragma unroll
        for (int j = 0; j < 4; j++) {
          float val = acc[i][j][r];
          float par = acc[i][j ^ 2][r];          // col d^32, same lane
          float2 cs = (j & 1) ? cs1 : cs0;
          float out = (j < 2) ? (val * cs.x - par * cs.y)
                              : (val * cs.x + par * cs.y);
          int h = (hbase + j * 16) >> 6;
          int d = j * 16 + lr;
          int bh = b * 16 + h;
          dst[((size_t)(bh * 2048 + t)) * 64 + d] = f2bf(out * scale);
        }
      }
    }
  } else {
    // v: write transposed vt[bh][d][t]; 4 r-values are contiguous t -> uint2 store
#pragma unroll
    for (int i = 0; i < 4; i++) {
      int tb = m0 + wm + i * 16 + lg * 4;
      int t0 = tb & 2047, b = tb >> 11;
#pragma unroll
      for (int j = 0; j < 4; j++) {
        int h = (hbase + j * 16) >> 6;
        int d = j * 16 + lr;
        int bh = b * 16 + h;
        unsigned short pv[4];
#pragma unroll
        for (int r = 0; r < 4; r++) pv[r] = f2bf(acc[i][j][r]);
        *(uint2*)&vt[((size_t)(bh * 64 + d)) * 2048 + t0] = *(uint2*)pv;
      }
    }
  }
}

// ============ proj GEMM: out[4096][1024] f32 = att[4096][1024] x wpt[1024][1024]^T ====
// 64x128 tile -> 512 blocks = 2/CU (vs 1/CU at 128^2). T1 XCD swizzle. 4 waves,
// wave w owns 64x32 (4x2 frags). BK=32, gl_lds staging, 64B LDS rows (conflict-free).
__global__ void k_gemm_proj(const unsigned short* __restrict__ A,
                            const unsigned short* __restrict__ Bt,
                            float* __restrict__ C) {
  const int K = 1024;
  __shared__ unsigned short Ta[64 * 32];
  __shared__ unsigned short Tb[128 * 32];
  const int tid = threadIdx.x;
  const int bid0 = blockIdx.x;                  // 512 blocks
  const int bid = (bid0 & 7) * 64 + (bid0 >> 3);
  const int n0 = (bid & 7) * 128;
  const int m0 = (bid >> 3) * 64;
  const int w = tid >> 6, l = tid & 63;
  const int lr = l & 15, lg = l >> 4;
  const int wn = w * 32;
  const int sra = tid >> 2, sca = (tid & 3) * 8;
  f32x4 acc[4][2] = {};
  for (int k0 = 0; k0 < K; k0 += 32) {
    __syncthreads();
    gl_lds16(&A[(size_t)(m0 + sra) * K + k0 + sca],        &Ta[tid * 8]);
    gl_lds16(&Bt[(size_t)(n0 + sra) * K + k0 + sca],       &Tb[tid * 8]);
    gl_lds16(&Bt[(size_t)(n0 + 64 + sra) * K + k0 + sca],  &Tb[(tid + 256) * 8]);
    __syncthreads();
    bf16x8 af[4], bfr[2];
#pragma unroll
    for (int i = 0; i < 4; i++)
      af[i] = *(const bf16x8*)&Ta[(i * 16 + lr) * 32 + lg * 8];
#pragma unroll
    for (int j = 0; j < 2; j++)
      bfr[j] = *(const bf16x8*)&Tb[(wn + j * 16 + lr) * 32 + lg * 8];
#pragma unroll
    for (int i = 0; i < 4; i++)
#pragma unroll
      for (int j = 0; j < 2; j++)
        acc[i][j] = __builtin_amdgcn_mfma_f32_16x16x32_bf16(af[i], bfr[j], acc[i][j], 0, 0, 0);
  }
#pragma unroll
  for (int i = 0; i < 4; i++)
#pragma unroll
    for (int j = 0; j < 2; j++)
#pragma unroll
      for (int r = 0; r < 4; r++)
        C[(size_t)(m0 + i * 16 + lg * 4 + r) * 1024 + n0 + wn + j * 16 + lr] = acc[i][j][r];
}

// ---------------- causal flash attention (round-3 verbatim: 43.8 us proven) ----------
__global__ __launch_bounds__(256, 2) void k_attn(const unsigned short* __restrict__ qh,
                       const unsigned short* __restrict__ kh,
                       const unsigned short* __restrict__ vt,
                       unsigned short* __restrict__ att) {
  __shared__ unsigned short Kl[64 * 64];   // [k][d]
  __shared__ unsigned short Vl[64 * 64];   // [d][k]  (V^T)
  __shared__ unsigned short Pl[4][16 * 64];// per-wave [q][k]
  const int bid = blockIdx.x;
  const int bh  = ((bid & 7) << 2) | ((bid >> 3) >> 4);   // head-major per XCD
  const int qt0 = (bid >> 3) & 15;
  const int qt1 = 31 - qt0;
  const int b = bh >> 4, h = bh & 15;
  const int tid = threadIdx.x;
  const int w = tid >> 6, l = tid & 63;
  const int lr = l & 15, lg = l >> 4;
  const unsigned short* qbase = qh + (size_t)bh * 2048 * 64;
  const unsigned short* kbase = kh + (size_t)bh * 2048 * 64;
  const unsigned short* vbase = vt + (size_t)bh * 64 * 2048;
  char* KB = (char*)Kl;
  char* VB = (char*)Vl;
  char* PB = (char*)&Pl[w][0];
  const int swz = (lr & 7) << 4;
  const int sr = tid >> 2, sc = (tid & 3) * 16;
  const int sb0 = (sr * 128 + sc * 2) ^ ((sr & 7) << 4);
  const int sb1 = (sr * 128 + sc * 2 + 16) ^ ((sr & 7) << 4);

  const int q00 = qt0 * 64, q01 = qt1 * 64;
  const int qrow0 = q00 + w * 16 + lr;
  const int qrow1 = q01 + w * 16 + lr;
  bf16x8 qa0 = *(const bf16x8*)&qbase[(size_t)qrow0 * 64 + lg * 8];
  bf16x8 qb0 = *(const bf16x8*)&qbase[(size_t)qrow0 * 64 + 32 + lg * 8];
  bf16x8 qa1 = *(const bf16x8*)&qbase[(size_t)qrow1 * 64 + lg * 8];
  bf16x8 qb1 = *(const bf16x8*)&qbase[(size_t)qrow1 * 64 + 32 + lg * 8];

  float mr0 = -3.0e38f, ls0 = 0.0f;
  float mr1 = -3.0e38f, ls1 = 0.0f;
  f32x4 of0[4] = {}, of1[4] = {};
  uint4 ka0, ka1, va0, va1;   // in-flight K/V tile (T14)

  auto issue = [&](int kv0) {
    const unsigned short* ksrc = &kbase[(size_t)(kv0 + sr) * 64 + sc];
    const unsigned short* vsrc = &vbase[(size_t)sr * 2048 + kv0 + sc];
    ka0 = *(const uint4*)ksrc; ka1 = *(const uint4*)(ksrc + 8);
    va0 = *(const uint4*)vsrc; va1 = *(const uint4*)(vsrc + 8);
  };

  auto step = [&](f32x4 (&of)[4], float& mr, float& ls, bf16x8 qa, bf16x8 qb,
                  int qrow, int kv0, bool diag) {
    f32x4 s[4] = {};
    __builtin_amdgcn_s_setprio(1);
#pragma unroll
    for (int kq = 0; kq < 4; kq++) {
      bf16x8 kf0 = *(const bf16x8*)(KB + (((kq * 16 + lr) * 128 + lg * 16) ^ swz));
      bf16x8 kf1 = *(const bf16x8*)(KB + (((kq * 16 + lr) * 128 + 64 + lg * 16) ^ swz));
      s[kq] = __builtin_amdgcn_mfma_f32_16x16x32_bf16(kf0, qa, s[kq], 0, 0, 0);
      s[kq] = __builtin_amdgcn_mfma_f32_16x16x32_bf16(kf1, qb, s[kq], 0, 0, 0);
    }
    __builtin_amdgcn_s_setprio(0);
    if (diag) {
#pragma unroll
      for (int kq = 0; kq < 4; kq++)
#pragma unroll
        for (int r = 0; r < 4; r++)
          if (kv0 + kq * 16 + lg * 4 + r > qrow) s[kq][r] = -3.0e38f;
    }
    float pm = s[0][0];
#pragma unroll
    for (int kq = 0; kq < 4; kq++)
#pragma unroll
      for (int r = 0; r < 4; r++) pm = fmaxf(pm, s[kq][r]);
    pm = fmaxf(pm, __shfl_xor(pm, 16));
    pm = fmaxf(pm, __shfl_xor(pm, 32));
    float mnew = fmaxf(mr, pm);
    float alpha = __builtin_amdgcn_exp2f(mr - mnew);
    mr = mnew;
    float psum = 0.0f;
#pragma unroll
    for (int kq = 0; kq < 4; kq++)
#pragma unroll
      for (int r = 0; r < 4; r++) {
        float p = __builtin_amdgcn_exp2f(s[kq][r] - mnew);
        s[kq][r] = p;
        psum += p;
      }
    psum += __shfl_xor(psum, 16);
    psum += __shfl_xor(psum, 32);
    ls = ls * alpha + psum;
#pragma unroll
    for (int n = 0; n < 4; n++) {
      of[n][0] *= alpha; of[n][1] *= alpha; of[n][2] *= alpha; of[n][3] *= alpha;
    }
    // P -> per-wave LDS [q][k] (wave-synchronous)
#pragma unroll
    for (int kq = 0; kq < 4; kq++) {
      uint2 pk;
      asm("v_cvt_pk_bf16_f32 %0, %1, %2" : "=v"(pk.x) : "v"(s[kq][0]), "v"(s[kq][1]));
      asm("v_cvt_pk_bf16_f32 %0, %1, %2" : "=v"(pk.y) : "v"(s[kq][2]), "v"(s[kq][3]));
      *(uint2*)(PB + ((lr * 128 + (kq * 16 + lg * 4) * 2) ^ swz)) = pk;
    }
    bf16x8 pb0 = *(const bf16x8*)(PB + ((lr * 128 + lg * 16) ^ swz));
    bf16x8 pb1 = *(const bf16x8*)(PB + ((lr * 128 + 64 + lg * 16) ^ swz));
    __builtin_amdgcn_s_setprio(1);
#pragma unroll
    for (int n = 0; n < 4; n++) {
      bf16x8 vf0 = *(const bf16x8*)(VB + (((n * 16 + lr) * 128 + lg * 16) ^ swz));
      bf16x8 vf1 = *(const bf16x8*)(VB + (((n * 16 + lr) * 128 + 64 + lg * 16) ^ swz));
      of[n] = __builtin_amdgcn_mfma_f32_16x16x32_bf16(vf0, pb0, of[n], 0, 0, 0);
      of[n] = __builtin_amdgcn_mfma_f32_16x16x32_bf16(vf1, pb1, of[n], 0, 0, 0);
    }
    __builtin_amdgcn_s_setprio(0);
  };

  issue(0);
  const int nkv0 = qt0 + 1;
  for (int s2 = 0; s2 < 33; s2++) {
    __syncthreads();
    *(uint4*)(KB + sb0) = ka0;  *(uint4*)(KB + sb1) = ka1;
    *(uint4*)(VB + sb0) = va0;  *(uint4*)(VB + sb1) = va1;
    __syncthreads();
    if (s2 < 32) {
      int ns = s2 + 1;
      issue(((ns < nkv0) ? ns : ns - nkv0) * 64);
    }
    if (s2 < nkv0) step(of0, mr0, ls0, qa0, qb0, qrow0, s2 * 64, s2 == qt0);
    else           step(of1, mr1, ls1, qa1, qb1, qrow1, (s2 - nkv0) * 64, s2 == 32);
  }

  auto store_half = [&](f32x4 (&of)[4], float ls, int q0) {
    float inv = 1.0f / ls;
#pragma unroll
    for (int n = 0; n < 4; n++) {
      uint2 pk;
      float o0 = of[n][0] * inv, o1 = of[n][1] * inv, o2 = of[n][2] * inv, o3 = of[n][3] * inv;
      asm("v_cvt_pk_bf16_f32 %0, %1, %2" : "=v"(pk.x) : "v"(o0), "v"(o1));
      asm("v_cvt_pk_bf16_f32 %0, %1, %2" : "=v"(pk.y) : "v"(o2), "v"(o3));
      *(uint2*)(PB + ((lr * 128 + (n * 16 + lg * 4) * 2) ^ swz)) = pk;
    }
    int r2 = l >> 2, c2 = (l & 3) * 16;
    int bo0 = (r2 * 128 + c2 * 2) ^ ((r2 & 7) << 4);
    int bo1 = (r2 * 128 + c2 * 2 + 16) ^ ((r2 & 7) << 4);
    uint4 o0 = *(const uint4*)(PB + bo0);
    uint4 o1 = *(const uint4*)(PB + bo1);
    unsigned short* orow = att + (size_t)(b * 2048 + q0 + w * 16 + r2) * 1024 + h * 64 + c2;
    *(uint4*)orow = o0;
    *(uint4*)(orow + 8) = o1;
  };
  store_half(of0, ls0, q00);
  store_half(of1, ls1, q01);
}

extern "C" void kernel_launch(void* const* d_in, const int* in_sizes, int n_in,
                              void* d_out, int out_size, void* d_ws, size_t ws_size,
                              hipStream_t stream) {
  const float* x     = (const float*)d_in[0];
  const float* Wqkv  = (const float*)d_in[1];
  const float* Wproj = (const float*)d_in[2];
  float* out = (float*)d_out;

  char* ws = (char*)d_ws;
  size_t off = 0;
  auto alloc = [&](size_t bytes) { void* p = ws + off; off += (bytes + 255) & ~(size_t)255; return p; };
  unsigned short* xb   = (unsigned short*)alloc((size_t)4096 * 1024 * 2);
  unsigned short* wqt  = (unsigned short*)alloc((size_t)3072 * 1024 * 2);
  unsigned short* wpt  = (unsigned short*)alloc((size_t)1024 * 1024 * 2);
  unsigned short* qh   = (unsigned short*)alloc((size_t)32 * 2048 * 64 * 2);
  unsigned short* kh   = (unsigned short*)alloc((size_t)32 * 2048 * 64 * 2);
  unsigned short* vt   = (unsigned short*)alloc((size_t)32 * 64 * 2048 * 2);
  unsigned short* att  = (unsigned short*)alloc((size_t)4096 * 1024 * 2);
  float2* cstab = (float2*)alloc((size_t)2048 * 32 * 8);

  k_prep<<<8448, 256, 0, stream>>>(x, Wqkv, Wproj, xb, wqt, wpt, cstab);
  k_gemm_qkv<<<dim3(24, 32), 256, 0, stream>>>(xb, wqt, cstab, qh, kh, vt);
  k_attn<<<512, 256, 0, stream>>>(qh, kh, vt, att);
  k_gemm_proj<<<512, 256, 0, stream>>>(att, wpt, out);
}